// Round 20
// baseline (1985.233 us; speedup 1.0000x reference)
//
#include <hip/hip_runtime.h>
#include <math.h>

#define NROWS  65536
#define DDIM   256
#define KCODES 512
#define NTH    512
#define NSTAGE 3
#define MARGIN  0.5f
#define MAXFLAG 32768
#define NLOSS   256
#define MB      64

typedef __attribute__((ext_vector_type(8))) short short8v;
typedef __attribute__((ext_vector_type(4))) float f32x4;

__device__ __forceinline__ unsigned short f2bf(float x) {
  unsigned int u = __float_as_uint(x);
  unsigned int r = (u + 0x7fffu + ((u >> 16) & 1u)) >> 16;
  return (unsigned short)r;
}

__device__ __forceinline__ void glds16(const void* g, void* l) {
  __builtin_amdgcn_global_load_lds(
      (const __attribute__((address_space(1))) unsigned int*)g,
      (__attribute__((address_space(3))) unsigned int*)l, 16, 0, 0);
}

// ---- np.sum(x*x,-1) model: dispatched pairwise_sum, AVX512F (r12 PASS — do not touch)
__device__ __forceinline__ float np_sumsq256(const float* p) {
#pragma clang fp contract(off)
  float blk[2];
#pragma unroll
  for (int b = 0; b < 2; ++b) {
    const float* a = p + b * 128;
    float v[16];
#pragma unroll
    for (int l = 0; l < 16; ++l) {
      float p0a = a[l] * a[l];
      float p0b = a[64 + l] * a[64 + l];
      float P0 = p0a + p0b;
      float p1a = a[16 + l] * a[16 + l];
      float p1b = a[80 + l] * a[80 + l];
      float P1 = p1a + p1b;
      float p2a = a[32 + l] * a[32 + l];
      float p2b = a[96 + l] * a[96 + l];
      float P2 = p2a + p2b;
      float p3a = a[48 + l] * a[48 + l];
      float p3b = a[112 + l] * a[112 + l];
      float P3 = p3a + p3b;
      v[l] = (P0 + P1) + (P2 + P3);
    }
    float s1[8];
#pragma unroll
    for (int l = 0; l < 8; ++l) s1[l] = v[l] + v[l + 8];
    float s2[4];
#pragma unroll
    for (int l = 0; l < 4; ++l) s2[l] = s1[l] + s1[l + 4];
    float s3_0 = s2[0] + s2[2];
    float s3_1 = s2[1] + s2[3];
    blk[b] = s3_0 + s3_1;
  }
  return blk[0] + blk[1];
}

// ---- np c_einsum dot model: baseline SSE3 (r12 PASS — do not touch)
__device__ __forceinline__ float np_einsum_dot256(const float* __restrict__ x,
                                                  const float* __restrict__ c) {
#pragma clang fp contract(off)
  float v[4] = {0.f, 0.f, 0.f, 0.f};
  for (int t = 0; t < 16; ++t) {
    const float* a = x + t * 16;
    const float* b = c + t * 16;
#pragma unroll
    for (int l = 0; l < 4; ++l) {
      float ab3 = a[12 + l] * b[12 + l] + v[l];
      float ab2 = a[8 + l] * b[8 + l] + ab3;
      float ab1 = a[4 + l] * b[4 + l] + ab2;
      v[l] = a[0 + l] * b[0 + l] + ab1;
    }
  }
  return (v[0] + v[1]) + (v[2] + v[3]);
}

// ---------------- codebook norms, np-bitwise ----------------
__global__ void cc_np_k(const float* __restrict__ c0, const float* __restrict__ c1,
                        const float* __restrict__ c2, float* __restrict__ cc) {
  int t = blockIdx.x * blockDim.x + threadIdx.x;
  if (t >= NSTAGE * KCODES) return;
  const float* cb = (t < KCODES) ? c0 : (t < 2 * KCODES ? c1 : c2);
  cc[t] = np_sumsq256(cb + (size_t)(t & (KCODES - 1)) * DDIM);
}

// ---------------- split codebooks -> bf16 HIGH only, FRAGMENT-ORDERED ----
// Per stage: [ctile 0..7][chunk 0..7][ct 0..3][lane 0..63] x 16B.
__global__ void split_cb_k(const float* __restrict__ c0, const float* __restrict__ c1,
                           const float* __restrict__ c2,
                           unsigned short* __restrict__ Ch) {
  int t = blockIdx.x * 256 + threadIdx.x;
  if (t >= NSTAGE * KCODES * 32) return;
  int s = t / (KCODES * 32);
  int rem = t - s * KCODES * 32;
  int code = rem >> 5;
  int gran = rem & 31;
  int chunk = gran >> 2;
  int g = gran & 3;
  int ctile = code >> 6;
  int ct = (code >> 4) & 3;
  int c16 = code & 15;
  const float* cb = (s == 0) ? c0 : (s == 1 ? c1 : c2);
  const float* src = cb + (size_t)code * DDIM + gran * 8;
  unsigned short hv[8];
#pragma unroll
  for (int j = 0; j < 8; ++j) hv[j] = f2bf(src[j]);
  size_t off = (size_t)s * 262144 +
               ((((size_t)(ctile * 8 + chunk) * 4 + ct) * 64) + (g * 16 + c16)) * 16;
  *(uint4*)((char*)Ch + off) = *(uint4*)hv;
}

// ---------------- chain_k: residual chain -> bf16-high LDS-image ----------------
__global__ __launch_bounds__(256) void chain_k(
    const float* __restrict__ data,
    const float* __restrict__ cbA, const float* __restrict__ cbB,
    const int* __restrict__ idxA, const int* __restrict__ idxB,
    int stage, char* __restrict__ AhG) {
  const int t = blockIdx.x * 256 + threadIdx.x;
  const int r = t >> 5;
  const int g = t & 31;
  const int k0 = g * 8;
  float res[8];
  {
#pragma clang fp contract(off)
    const size_t base = (size_t)r * DDIM + k0;
    int iA = 0, iB = 0;
    if (stage >= 1) iA = idxA[r];
    if (stage == 2) iB = idxB[r];
#pragma unroll
    for (int half = 0; half < 2; ++half) {
      float4 dv = *(const float4*)(data + base + half * 4);
      float x1[4] = {dv.x, dv.y, dv.z, dv.w};
      float rr[4];
      if (stage == 0) {
#pragma unroll
        for (int j = 0; j < 4; ++j) rr[j] = x1[j];
      } else {
        float4 av = *(const float4*)(cbA + (size_t)iA * DDIM + k0 + half * 4);
        float af[4] = {av.x, av.y, av.z, av.w};
        float a[4];
#pragma unroll
        for (int j = 0; j < 4; ++j) a[j] = x1[j] + (af[j] - x1[j]);
        if (stage == 2) {
          float4 bv = *(const float4*)(cbB + (size_t)iB * DDIM + k0 + half * 4);
          float bf[4] = {bv.x, bv.y, bv.z, bv.w};
#pragma unroll
          for (int j = 0; j < 4; ++j) {
            float x2 = x1[j] - a[j];
            float qst2 = x2 + (bf[j] - x2);
            a[j] = a[j] + qst2;
          }
        }
#pragma unroll
        for (int j = 0; j < 4; ++j) rr[j] = x1[j] - a[j];
      }
#pragma unroll
      for (int j = 0; j < 4; ++j) res[half * 4 + j] = rr[j];
    }
  }
  unsigned short hv[8];
#pragma unroll
  for (int j = 0; j < 8; ++j) hv[j] = f2bf(res[j]);
  const int blk = r >> 6, lr = r & 63;
  const size_t byte = (size_t)blk * 32768 + ((lr * 512 + g * 16) ^ ((lr & 7) << 4));
  *(uint4*)(AhG + byte) = *(uint4*)hv;
}

// ---------------- gemm_k: single-pass bf16, glds A, direct-L2 B, top-2 ----
#define A_H_OFF 0
#define RED_OFF 32768
#define SMEM_SZ 40960

__global__ __launch_bounds__(NTH, 1) void gemm_k(
    const char* __restrict__ AhG,
    const unsigned short* __restrict__ Chf,
    const float* __restrict__ ccs,
    int* __restrict__ idx_out, unsigned int* __restrict__ flagcnt,
    int* __restrict__ flagrows) {
  __shared__ char smem[SMEM_SZ];

  const int tid = threadIdx.x;
  const int lane = tid & 63;
  const int w = tid >> 6;
  const int blk = blockIdx.x;
  const int rowbase = blk * MB;

  // stage A image (32KB) via global_load_lds
  {
    const char* gh = AhG + (size_t)blk * 32768;
    const int off0 = w * 1024 + lane * 16;
#pragma unroll
    for (int rr2 = 0; rr2 < 4; ++rr2)
      glds16(gh + rr2 * 8192 + off0, smem + A_H_OFF + rr2 * 8192 + off0);
  }

  f32x4 acc[4][4];
#pragma unroll
  for (int rt = 0; rt < 4; ++rt)
#pragma unroll
    for (int ct = 0; ct < 4; ++ct) {
      acc[rt][ct].x = 0.f; acc[rt][ct].y = 0.f;
      acc[rt][ct].z = 0.f; acc[rt][ct].w = 0.f;
    }

  const int g = lane >> 4, c16 = lane & 15;
  const char* bhw = (const char*)Chf + lane * 16;

  __syncthreads();   // drains glds; A visible

#pragma clang loop unroll(disable)
  for (int chunk = 0; chunk < 8; ++chunk) {
    short8v ah[4];
#pragma unroll
    for (int rt = 0; rt < 4; ++rt) {
      const int row = rt * 16 + c16;
      const int byte = (row * 512 + (chunk * 4 + g) * 16) ^ ((row & 7) << 4);
      ah[rt] = *(short8v*)(smem + A_H_OFF + byte);
    }
#pragma unroll
    for (int ct = 0; ct < 4; ++ct) {
      short8v bh = *(const short8v*)(bhw + (size_t)((w * 8 + chunk) * 4 + ct) * 1024);
#pragma unroll
      for (int rt = 0; rt < 4; ++rt)
        acc[rt][ct] = __builtin_amdgcn_mfma_f32_16x16x32_bf16(ah[rt], bh, acc[rt][ct], 0, 0, 0);
    }
  }
  __syncthreads();   // A reads done; red buffer reuse safe

  // ---- epilogue: d = cc - 2*dot, top-2 per row -> idx + flag
  float ccv[4];
#pragma unroll
  for (int ct = 0; ct < 4; ++ct) ccv[ct] = ccs[w * 64 + ct * 16 + c16];

  float* red = (float*)(smem + RED_OFF);  // [64 rows][8 waves][4 f32]
#pragma unroll
  for (int rt = 0; rt < 4; ++rt) {
#pragma unroll
    for (int reg = 0; reg < 4; ++reg) {
      const int row = rt * 16 + g * 4 + reg;
      float v1 = 3.0e38f, v2 = 3.0e38f;
      int i1 = 0x7fffffff;
#pragma unroll
      for (int ct = 0; ct < 4; ++ct) {
        const int col = w * 64 + ct * 16 + c16;
        float dd = ccv[ct] - 2.0f * acc[rt][ct][reg];
        if (dd < v1 || (dd == v1 && col < i1)) { v2 = v1; v1 = dd; i1 = col; }
        else if (dd < v2) v2 = dd;
      }
#pragma unroll
      for (int m = 1; m < 16; m <<= 1) {
        float ov1 = __shfl_xor(v1, m, 64);
        int oi1 = __shfl_xor(i1, m, 64);
        float ov2 = __shfl_xor(v2, m, 64);
        float worst = fmaxf(v1, ov1);
        v2 = fminf(fminf(v2, ov2), worst);
        if (ov1 < v1 || (ov1 == v1 && oi1 < i1)) { v1 = ov1; i1 = oi1; }
      }
      if (c16 == 0) {
        float* slot = red + (size_t)(row * 8 + w) * 4;
        slot[0] = v1;
        ((int*)slot)[1] = i1;
        slot[2] = v2;
      }
    }
  }
  __syncthreads();
  if (tid < MB) {
    float v1 = 3.0e38f, v2 = 3.0e38f;
    int i1 = 0x7fffffff;
#pragma unroll
    for (int ww = 0; ww < 8; ++ww) {
      const float* slot = red + (size_t)(tid * 8 + ww) * 4;
      float ov1 = slot[0];
      int oi1 = ((const int*)slot)[1];
      float ov2 = slot[2];
      float worst = fmaxf(v1, ov1);
      v2 = fminf(fminf(v2, ov2), worst);
      if (ov1 < v1 || (ov1 == v1 && oi1 < i1)) { v1 = ov1; i1 = oi1; }
    }
    const int r = rowbase + tid;
    idx_out[r] = i1;
    if (v2 - v1 < MARGIN) {
      unsigned pos = atomicAdd(flagcnt, 1u);
      if (pos < MAXFLAG) flagrows[pos] = r;
    }
  }
}

// ---------------- np-bitwise refine for flagged rows (r12 PASS) ----------------
__global__ __launch_bounds__(256) void refine_k(
    const float* __restrict__ data, const float* __restrict__ cb,
    const float* __restrict__ cbA, const float* __restrict__ cbB,
    const int* __restrict__ idxA, const int* __restrict__ idxB,
    const float* __restrict__ ccs, int stage,
    const unsigned int* __restrict__ flagcnt, const int* __restrict__ flagrows,
    int* __restrict__ idx_out) {
  __shared__ float rl[DDIM];
  __shared__ float xxs;
  __shared__ float red_v[256];
  __shared__ int red_i[256];

  unsigned int n = *flagcnt;
  if (n > MAXFLAG) n = MAXFLAG;
  const int tid = threadIdx.x;

  for (unsigned f = blockIdx.x; f < n; f += gridDim.x) {
    const int r = flagrows[f];
    if (tid < 64) {
#pragma clang fp contract(off)
      const size_t base = (size_t)r * DDIM + tid * 4;
      float4 dv = *(const float4*)(data + base);
      float x1[4] = {dv.x, dv.y, dv.z, dv.w};
      float res[4];
      if (stage == 0) {
#pragma unroll
        for (int j = 0; j < 4; ++j) res[j] = x1[j];
      } else {
        const int iA = idxA[r];
        float4 av = *(const float4*)(cbA + (size_t)iA * DDIM + tid * 4);
        float af[4] = {av.x, av.y, av.z, av.w};
        float a[4];
#pragma unroll
        for (int j = 0; j < 4; ++j) a[j] = x1[j] + (af[j] - x1[j]);
        if (stage == 2) {
          const int iB = idxB[r];
          float4 bv = *(const float4*)(cbB + (size_t)iB * DDIM + tid * 4);
          float bf[4] = {bv.x, bv.y, bv.z, bv.w};
#pragma unroll
          for (int j = 0; j < 4; ++j) {
            float x2 = x1[j] - a[j];
            float qst2 = x2 + (bf[j] - x2);
            a[j] = a[j] + qst2;
          }
        }
#pragma unroll
        for (int j = 0; j < 4; ++j) res[j] = x1[j] - a[j];
      }
#pragma unroll
      for (int j = 0; j < 4; ++j) rl[tid * 4 + j] = res[j];
    }
    __syncthreads();
    if (tid == 0) xxs = np_sumsq256(rl);
    __syncthreads();

    float bv = 3.0e38f;
    int bi = 0x7fffffff;
#pragma unroll
    for (int h = 0; h < 2; ++h) {
      const int k = tid + h * 256;
      float d;
      {
#pragma clang fp contract(off)
        float dot = np_einsum_dot256(rl, cb + (size_t)k * DDIM);
        float t1 = xxs - 2.0f * dot;
        d = t1 + ccs[k];
      }
      if (d < bv || (d == bv && k < bi)) { bv = d; bi = k; }
    }
    red_v[tid] = bv;
    red_i[tid] = bi;
    __syncthreads();
    for (int sgap = 128; sgap > 0; sgap >>= 1) {
      if (tid < sgap) {
        float o = red_v[tid + sgap];
        int oi = red_i[tid + sgap];
        if (o < red_v[tid] || (o == red_v[tid] && oi < red_i[tid])) {
          red_v[tid] = o;
          red_i[tid] = oi;
        }
      }
      __syncthreads();
    }
    if (tid == 0) idx_out[r] = red_i[0];
    __syncthreads();
  }
}

// ---------------- slim final: quant + loss + hist + one-hot SCATTER ----
__global__ __launch_bounds__(256) void final_k(
    const float* __restrict__ data, const float* __restrict__ cb0,
    const float* __restrict__ cb1, const float* __restrict__ cb2,
    const int* __restrict__ idx0, const int* __restrict__ idx1,
    const int* __restrict__ idx2, float* __restrict__ quant,
    float* __restrict__ enc0, float* __restrict__ enc1,
    float* __restrict__ enc2, double* __restrict__ loss_slots,
    unsigned int* __restrict__ hist) {
  __shared__ double wsum[4];
  const int lane = threadIdx.x & 63;
  const int w = threadIdx.x >> 6;
  const int r = blockIdx.x * 4 + w;
  const int i0 = idx0[r], i1 = idx1[r], i2 = idx2[r];
  const size_t base = (size_t)r * DDIM + lane * 4;
  float4 dv = *(const float4*)(data + base);
  float4 c0v = *(const float4*)(cb0 + (size_t)i0 * DDIM + lane * 4);
  float4 c1v = *(const float4*)(cb1 + (size_t)i1 * DDIM + lane * 4);
  float4 c2v = *(const float4*)(cb2 + (size_t)i2 * DDIM + lane * 4);
  float df[4] = {dv.x, dv.y, dv.z, dv.w};
  float q0f[4] = {c0v.x, c0v.y, c0v.z, c0v.w};
  float q1f[4] = {c1v.x, c1v.y, c1v.z, c1v.w};
  float q2f[4] = {c2v.x, c2v.y, c2v.z, c2v.w};
  float qout[4];
  double lsum = 0.0;
  {
#pragma clang fp contract(off)
#pragma unroll
    for (int j = 0; j < 4; ++j) {
      float x1 = df[j];
      float d1 = q0f[j] - x1;
      float qst1 = x1 + d1;
      float a1 = qst1;
      float x2 = x1 - a1;
      float d2 = q1f[j] - x2;
      float qst2 = x2 + d2;
      float a2 = a1 + qst2;
      float x3 = x1 - a2;
      float d3 = q2f[j] - x3;
      float qst3 = x3 + d3;
      float a3 = a2 + qst3;
      qout[j] = a3;
      lsum += (double)d1 * d1 + (double)d2 * d2 + (double)d3 * d3;
    }
  }
  float4 qv = {qout[0], qout[1], qout[2], qout[3]};
  *(float4*)(quant + base) = qv;

#pragma unroll
  for (int off = 1; off < 64; off <<= 1) lsum += __shfl_xor(lsum, off, 64);
  if (lane == 0) {
    wsum[w] = lsum;
    enc0[(size_t)r * KCODES + i0] = 1.0f;
    atomicAdd(&hist[i0], 1u);
  } else if (lane == 1) {
    enc1[(size_t)r * KCODES + i1] = 1.0f;
    atomicAdd(&hist[KCODES + i1], 1u);
  } else if (lane == 2) {
    enc2[(size_t)r * KCODES + i2] = 1.0f;
    atomicAdd(&hist[2 * KCODES + i2], 1u);
  }
  __syncthreads();
  if (threadIdx.x == 0) {
    double bsum = (wsum[0] + wsum[1]) + (wsum[2] + wsum[3]);
    atomicAdd(&loss_slots[blockIdx.x & (NLOSS - 1)], bsum);
  }
}

// ---------------- scalars ----------------
__global__ void finalize_k(const unsigned int* __restrict__ hist,
                           const double* __restrict__ loss_slots,
                           float* __restrict__ out_scalars) {
  int lane = threadIdx.x;  // 64 threads
  double te = 0.0;
  for (int s = 0; s < NSTAGE; ++s) {
    double e = 0.0;
    for (int j = 0; j < KCODES / 64; ++j) {
      int k = j * 64 + lane;
      float pf = (float)hist[s * KCODES + k] * (1.0f / 65536.0f);
      float sf = __fadd_rn(pf, 1e-10f);
      e += (double)pf * log((double)sf);
    }
#pragma unroll
    for (int off = 1; off < 64; off <<= 1) e += __shfl_xor(e, off, 64);
    te += -e;
  }
  double ls = loss_slots[lane] + loss_slots[64 + lane] +
              loss_slots[128 + lane] + loss_slots[192 + lane];
#pragma unroll
  for (int off = 1; off < 64; off <<= 1) ls += __shfl_xor(ls, off, 64);
  if (lane == 0) {
    double tl = 1.25 * ls * (1.0 / 16777216.0);
    out_scalars[0] = (float)tl;
    out_scalars[1] = (float)te;
  }
}

extern "C" void kernel_launch(void* const* d_in, const int* in_sizes, int n_in,
                              void* d_out, int out_size, void* d_ws, size_t ws_size,
                              hipStream_t stream) {
  const float* data = (const float*)d_in[0];
  const float* cb0 = (const float*)d_in[1];
  const float* cb1 = (const float*)d_in[2];
  const float* cb2 = (const float*)d_in[3];
  const float* cbs[3] = {cb0, cb1, cb2};
  float* out = (float*)d_out;
  float* quant = out;
  float* enc0 = out + (size_t)NROWS * DDIM;
  float* enc1 = enc0 + (size_t)NROWS * KCODES;
  float* enc2 = enc1 + (size_t)NROWS * KCODES;
  float* out_scalars = enc2 + (size_t)NROWS * KCODES;

  // A-image scratch in enc0 output region (memset after stage loop wipes it)
  char* AhG = (char*)enc0;                // 32 MB

  // ws: [0) loss_slots f64x256 | 2048) hist u32x1536 | 8192) flagcnt u32x3 |
  //     8320) flagrows i32[3][32768] | 401536) cc f32x1536 |
  //     407680) idx i32[3][N] | 1194112) Ch frag-bf16 3x256KB
  double* loss_slots = (double*)d_ws;
  unsigned int* hist = (unsigned int*)((char*)d_ws + 2048);
  unsigned int* flagcnt = (unsigned int*)((char*)d_ws + 8192);
  int* flagrows = (int*)((char*)d_ws + 8320);
  float* cc = (float*)((char*)d_ws + 401536);
  int* idx0 = (int*)((char*)d_ws + 407680);
  int* idx1 = idx0 + NROWS;
  int* idx2 = idx1 + NROWS;
  int* idxs[3] = {idx0, idx1, idx2};
  unsigned short* Ch = (unsigned short*)((char*)d_ws + 1194112);

  hipMemsetAsync(d_ws, 0, 8320, stream);

  cc_np_k<<<(NSTAGE * KCODES + 255) / 256, 256, 0, stream>>>(cb0, cb1, cb2, cc);
  split_cb_k<<<(NSTAGE * KCODES * 32 + 255) / 256, 256, 0, stream>>>(
      cb0, cb1, cb2, Ch);

  for (int s = 0; s < NSTAGE; ++s) {
    chain_k<<<NROWS * 32 / 256, 256, 0, stream>>>(
        data, cb0, cb1, idx0, idx1, s, AhG);
    gemm_k<<<NROWS / MB, NTH, 0, stream>>>(
        AhG,
        (const unsigned short*)((char*)Ch + (size_t)s * 262144),
        cc + s * KCODES, idxs[s], flagcnt + s, flagrows + s * MAXFLAG);
    refine_k<<<1024, 256, 0, stream>>>(
        data, cbs[s], cb0, cb1, idx0, idx1, cc + s * KCODES, s,
        flagcnt + s, flagrows + s * MAXFLAG, idxs[s]);
  }

  // zero enc region (also wipes A-image scratch), then scatter the 1s
  hipMemsetAsync(enc0, 0, (size_t)3 * NROWS * KCODES * sizeof(float), stream);

  final_k<<<NROWS / 4, 256, 0, stream>>>(
      data, cb0, cb1, cb2, idx0, idx1, idx2, quant, enc0, enc1, enc2,
      loss_slots, hist);

  finalize_k<<<1, 64, 0, stream>>>(hist, loss_slots, out_scalars);
}

// Round 21
// 537.251 us; speedup vs baseline: 3.6952x; 3.6952x over previous
//
#include <hip/hip_runtime.h>
#include <math.h>

#define NROWS  65536
#define DDIM   256
#define KCODES 512
#define NTH    512
#define NSTAGE 3
#define MARGIN  0.5f
#define MAXFLAG 65536
#define NLOSS   256
#define MB      64
#define RB      8      // refine rows per block-batch

typedef __attribute__((ext_vector_type(8))) short short8v;
typedef __attribute__((ext_vector_type(4))) float f32x4;

__device__ __forceinline__ unsigned short f2bf(float x) {
  unsigned int u = __float_as_uint(x);
  unsigned int r = (u + 0x7fffu + ((u >> 16) & 1u)) >> 16;
  return (unsigned short)r;
}

__device__ __forceinline__ void glds16(const void* g, void* l) {
  __builtin_amdgcn_global_load_lds(
      (const __attribute__((address_space(1))) unsigned int*)g,
      (__attribute__((address_space(3))) unsigned int*)l, 16, 0, 0);
}

// ---- np.sum(x*x,-1) model: dispatched pairwise_sum, AVX512F (r12 PASS — do not touch)
__device__ __forceinline__ float np_sumsq256(const float* p) {
#pragma clang fp contract(off)
  float blk[2];
#pragma unroll
  for (int b = 0; b < 2; ++b) {
    const float* a = p + b * 128;
    float v[16];
#pragma unroll
    for (int l = 0; l < 16; ++l) {
      float p0a = a[l] * a[l];
      float p0b = a[64 + l] * a[64 + l];
      float P0 = p0a + p0b;
      float p1a = a[16 + l] * a[16 + l];
      float p1b = a[80 + l] * a[80 + l];
      float P1 = p1a + p1b;
      float p2a = a[32 + l] * a[32 + l];
      float p2b = a[96 + l] * a[96 + l];
      float P2 = p2a + p2b;
      float p3a = a[48 + l] * a[48 + l];
      float p3b = a[112 + l] * a[112 + l];
      float P3 = p3a + p3b;
      v[l] = (P0 + P1) + (P2 + P3);
    }
    float s1[8];
#pragma unroll
    for (int l = 0; l < 8; ++l) s1[l] = v[l] + v[l + 8];
    float s2[4];
#pragma unroll
    for (int l = 0; l < 4; ++l) s2[l] = s1[l] + s1[l + 4];
    float s3_0 = s2[0] + s2[2];
    float s3_1 = s2[1] + s2[3];
    blk[b] = s3_0 + s3_1;
  }
  return blk[0] + blk[1];
}

// ---------------- codebook norms, np-bitwise ----------------
__global__ void cc_np_k(const float* __restrict__ c0, const float* __restrict__ c1,
                        const float* __restrict__ c2, float* __restrict__ cc) {
  int t = blockIdx.x * blockDim.x + threadIdx.x;
  if (t >= NSTAGE * KCODES) return;
  const float* cb = (t < KCODES) ? c0 : (t < 2 * KCODES ? c1 : c2);
  cc[t] = np_sumsq256(cb + (size_t)(t & (KCODES - 1)) * DDIM);
}

// ---------------- split codebooks -> bf16 HIGH only, FRAGMENT-ORDERED ----
__global__ void split_cb_k(const float* __restrict__ c0, const float* __restrict__ c1,
                           const float* __restrict__ c2,
                           unsigned short* __restrict__ Ch) {
  int t = blockIdx.x * 256 + threadIdx.x;
  if (t >= NSTAGE * KCODES * 32) return;
  int s = t / (KCODES * 32);
  int rem = t - s * KCODES * 32;
  int code = rem >> 5;
  int gran = rem & 31;
  int chunk = gran >> 2;
  int g = gran & 3;
  int ctile = code >> 6;
  int ct = (code >> 4) & 3;
  int c16 = code & 15;
  const float* cb = (s == 0) ? c0 : (s == 1 ? c1 : c2);
  const float* src = cb + (size_t)code * DDIM + gran * 8;
  unsigned short hv[8];
#pragma unroll
  for (int j = 0; j < 8; ++j) hv[j] = f2bf(src[j]);
  size_t off = (size_t)s * 262144 +
               ((((size_t)(ctile * 8 + chunk) * 4 + ct) * 64) + (g * 16 + c16)) * 16;
  *(uint4*)((char*)Ch + off) = *(uint4*)hv;
}

// ---------------- chain_k: residual chain -> bf16-high LDS-image ----------------
__global__ __launch_bounds__(256) void chain_k(
    const float* __restrict__ data,
    const float* __restrict__ cbA, const float* __restrict__ cbB,
    const int* __restrict__ idxA, const int* __restrict__ idxB,
    int stage, char* __restrict__ AhG) {
  const int t = blockIdx.x * 256 + threadIdx.x;
  const int r = t >> 5;
  const int g = t & 31;
  const int k0 = g * 8;
  float res[8];
  {
#pragma clang fp contract(off)
    const size_t base = (size_t)r * DDIM + k0;
    int iA = 0, iB = 0;
    if (stage >= 1) iA = idxA[r];
    if (stage == 2) iB = idxB[r];
#pragma unroll
    for (int half = 0; half < 2; ++half) {
      float4 dv = *(const float4*)(data + base + half * 4);
      float x1[4] = {dv.x, dv.y, dv.z, dv.w};
      float rr[4];
      if (stage == 0) {
#pragma unroll
        for (int j = 0; j < 4; ++j) rr[j] = x1[j];
      } else {
        float4 av = *(const float4*)(cbA + (size_t)iA * DDIM + k0 + half * 4);
        float af[4] = {av.x, av.y, av.z, av.w};
        float a[4];
#pragma unroll
        for (int j = 0; j < 4; ++j) a[j] = x1[j] + (af[j] - x1[j]);
        if (stage == 2) {
          float4 bv = *(const float4*)(cbB + (size_t)iB * DDIM + k0 + half * 4);
          float bf[4] = {bv.x, bv.y, bv.z, bv.w};
#pragma unroll
          for (int j = 0; j < 4; ++j) {
            float x2 = x1[j] - a[j];
            float qst2 = x2 + (bf[j] - x2);
            a[j] = a[j] + qst2;
          }
        }
#pragma unroll
        for (int j = 0; j < 4; ++j) rr[j] = x1[j] - a[j];
      }
#pragma unroll
      for (int j = 0; j < 4; ++j) res[half * 4 + j] = rr[j];
    }
  }
  unsigned short hv[8];
#pragma unroll
  for (int j = 0; j < 8; ++j) hv[j] = f2bf(res[j]);
  const int blk = r >> 6, lr = r & 63;
  const size_t byte = (size_t)blk * 32768 + ((lr * 512 + g * 16) ^ ((lr & 7) << 4));
  *(uint4*)(AhG + byte) = *(uint4*)hv;
}

// ---------------- gemm_k: single-pass bf16, glds A, direct-L2 B, top-2 ----
#define A_H_OFF 0
#define RED_OFF 32768
#define SMEM_SZ 40960

__global__ __launch_bounds__(NTH, 1) void gemm_k(
    const char* __restrict__ AhG,
    const unsigned short* __restrict__ Chf,
    const float* __restrict__ ccs,
    int* __restrict__ idx_out, unsigned int* __restrict__ flagcnt,
    int* __restrict__ flagrows) {
  __shared__ char smem[SMEM_SZ];

  const int tid = threadIdx.x;
  const int lane = tid & 63;
  const int w = tid >> 6;
  const int blk = blockIdx.x;
  const int rowbase = blk * MB;

  {
    const char* gh = AhG + (size_t)blk * 32768;
    const int off0 = w * 1024 + lane * 16;
#pragma unroll
    for (int rr2 = 0; rr2 < 4; ++rr2)
      glds16(gh + rr2 * 8192 + off0, smem + A_H_OFF + rr2 * 8192 + off0);
  }

  f32x4 acc[4][4];
#pragma unroll
  for (int rt = 0; rt < 4; ++rt)
#pragma unroll
    for (int ct = 0; ct < 4; ++ct) {
      acc[rt][ct].x = 0.f; acc[rt][ct].y = 0.f;
      acc[rt][ct].z = 0.f; acc[rt][ct].w = 0.f;
    }

  const int g = lane >> 4, c16 = lane & 15;
  const char* bhw = (const char*)Chf + lane * 16;

  __syncthreads();

#pragma clang loop unroll(disable)
  for (int chunk = 0; chunk < 8; ++chunk) {
    short8v ah[4];
#pragma unroll
    for (int rt = 0; rt < 4; ++rt) {
      const int row = rt * 16 + c16;
      const int byte = (row * 512 + (chunk * 4 + g) * 16) ^ ((row & 7) << 4);
      ah[rt] = *(short8v*)(smem + A_H_OFF + byte);
    }
#pragma unroll
    for (int ct = 0; ct < 4; ++ct) {
      short8v bh = *(const short8v*)(bhw + (size_t)((w * 8 + chunk) * 4 + ct) * 1024);
#pragma unroll
      for (int rt = 0; rt < 4; ++rt)
        acc[rt][ct] = __builtin_amdgcn_mfma_f32_16x16x32_bf16(ah[rt], bh, acc[rt][ct], 0, 0, 0);
    }
  }
  __syncthreads();

  float ccv[4];
#pragma unroll
  for (int ct = 0; ct < 4; ++ct) ccv[ct] = ccs[w * 64 + ct * 16 + c16];

  float* red = (float*)(smem + RED_OFF);
#pragma unroll
  for (int rt = 0; rt < 4; ++rt) {
#pragma unroll
    for (int reg = 0; reg < 4; ++reg) {
      const int row = rt * 16 + g * 4 + reg;
      float v1 = 3.0e38f, v2 = 3.0e38f;
      int i1 = 0x7fffffff;
#pragma unroll
      for (int ct = 0; ct < 4; ++ct) {
        const int col = w * 64 + ct * 16 + c16;
        float dd = ccv[ct] - 2.0f * acc[rt][ct][reg];
        if (dd < v1 || (dd == v1 && col < i1)) { v2 = v1; v1 = dd; i1 = col; }
        else if (dd < v2) v2 = dd;
      }
#pragma unroll
      for (int m = 1; m < 16; m <<= 1) {
        float ov1 = __shfl_xor(v1, m, 64);
        int oi1 = __shfl_xor(i1, m, 64);
        float ov2 = __shfl_xor(v2, m, 64);
        float worst = fmaxf(v1, ov1);
        v2 = fminf(fminf(v2, ov2), worst);
        if (ov1 < v1 || (ov1 == v1 && oi1 < i1)) { v1 = ov1; i1 = oi1; }
      }
      if (c16 == 0) {
        float* slot = red + (size_t)(row * 8 + w) * 4;
        slot[0] = v1;
        ((int*)slot)[1] = i1;
        slot[2] = v2;
      }
    }
  }
  __syncthreads();
  if (tid < MB) {
    float v1 = 3.0e38f, v2 = 3.0e38f;
    int i1 = 0x7fffffff;
#pragma unroll
    for (int ww = 0; ww < 8; ++ww) {
      const float* slot = red + (size_t)(tid * 8 + ww) * 4;
      float ov1 = slot[0];
      int oi1 = ((const int*)slot)[1];
      float ov2 = slot[2];
      float worst = fmaxf(v1, ov1);
      v2 = fminf(fminf(v2, ov2), worst);
      if (ov1 < v1 || (ov1 == v1 && oi1 < i1)) { v1 = ov1; i1 = oi1; }
    }
    const int r = rowbase + tid;
    idx_out[r] = i1;
    if (v2 - v1 < MARGIN) {
      unsigned pos = atomicAdd(flagcnt, 1u);
      if (pos < MAXFLAG) flagrows[pos] = r;
    }
  }
}

// ---------------- refine v2: batched RB rows/block-iter, np-bitwise ----------
// Per batch: stage RB flagged rows' residual chains (np f32) + np-pairwise xx
// in LDS; each thread owns codes {tid, tid+256}, keeps v[RB][4] einsum
// accumulators (npyv-SSE3 reverse-chain model), streams its code rows ONCE;
// per-row block tree-reduce -> exact argmin.
__global__ __launch_bounds__(256) void refine_k(
    const float* __restrict__ data, const float* __restrict__ cb,
    const float* __restrict__ cbA, const float* __restrict__ cbB,
    const int* __restrict__ idxA, const int* __restrict__ idxB,
    const float* __restrict__ ccs, int stage,
    const unsigned int* __restrict__ flagcnt, const int* __restrict__ flagrows,
    int* __restrict__ idx_out) {
  __shared__ float rows[RB][DDIM];   // 8 KB
  __shared__ float xxs[RB];
  __shared__ float red_v[RB][256];   // 8 KB
  __shared__ int red_i[RB][256];     // 8 KB

  unsigned int n = *flagcnt;
  if (n > MAXFLAG) n = MAXFLAG;      // MAXFLAG==NROWS: never clamps
  const int tid = threadIdx.x;

  for (unsigned base = (unsigned)blockIdx.x * RB; base < n;
       base += (unsigned)gridDim.x * RB) {
    const int nb = (int)min((unsigned)RB, n - base);

    // ---- stage nb rows' residual chains (np f32 op order)
    for (int u = tid; u < nb * 64; u += 256) {
#pragma clang fp contract(off)
      const int i = u >> 6;
      const int c4 = (u & 63) * 4;
      const int r = flagrows[base + i];
      const size_t gbase = (size_t)r * DDIM + c4;
      float4 dv = *(const float4*)(data + gbase);
      float x1[4] = {dv.x, dv.y, dv.z, dv.w};
      float res[4];
      if (stage == 0) {
#pragma unroll
        for (int j = 0; j < 4; ++j) res[j] = x1[j];
      } else {
        const int iA = idxA[r];
        float4 av = *(const float4*)(cbA + (size_t)iA * DDIM + c4);
        float af[4] = {av.x, av.y, av.z, av.w};
        float a[4];
#pragma unroll
        for (int j = 0; j < 4; ++j) a[j] = x1[j] + (af[j] - x1[j]);
        if (stage == 2) {
          const int iB = idxB[r];
          float4 bv = *(const float4*)(cbB + (size_t)iB * DDIM + c4);
          float bf[4] = {bv.x, bv.y, bv.z, bv.w};
#pragma unroll
          for (int j = 0; j < 4; ++j) {
            float x2 = x1[j] - a[j];
            float qst2 = x2 + (bf[j] - x2);
            a[j] = a[j] + qst2;
          }
        }
#pragma unroll
        for (int j = 0; j < 4; ++j) res[j] = x1[j] - a[j];
      }
#pragma unroll
      for (int j = 0; j < 4; ++j) rows[i][c4 + j] = res[j];
    }
    __syncthreads();
    if (tid < nb) xxs[tid] = np_sumsq256(rows[tid]);
    __syncthreads();

    // ---- each thread: 2 codes vs RB rows, np einsum (SSE3 reverse-chain)
    float bv[RB];
    int bi[RB];
#pragma unroll
    for (int i = 0; i < RB; ++i) { bv[i] = 3.0e38f; bi[i] = 0x7fffffff; }

#pragma clang loop unroll(disable)
    for (int h = 0; h < 2; ++h) {
#pragma clang fp contract(off)
      const int k = tid + h * 256;
      const float* crow = cb + (size_t)k * DDIM;
      float v[RB][4];
#pragma unroll
      for (int i = 0; i < RB; ++i)
#pragma unroll
        for (int l = 0; l < 4; ++l) v[i][l] = 0.f;

#pragma clang loop unroll(disable)
      for (int t = 0; t < 16; ++t) {
        float b[16];
#pragma unroll
        for (int j = 0; j < 16; ++j) b[j] = crow[t * 16 + j];
#pragma unroll
        for (int i = 0; i < RB; ++i) {
#pragma unroll
          for (int l = 0; l < 4; ++l) {
            float a0 = rows[i][t * 16 + l];
            float a1 = rows[i][t * 16 + 4 + l];
            float a2 = rows[i][t * 16 + 8 + l];
            float a3 = rows[i][t * 16 + 12 + l];
            float ab3 = a3 * b[12 + l] + v[i][l];
            float ab2 = a2 * b[8 + l] + ab3;
            float ab1 = a1 * b[4 + l] + ab2;
            v[i][l] = a0 * b[l] + ab1;
          }
        }
      }
      const float cck = ccs[k];
#pragma unroll
      for (int i = 0; i < RB; ++i) {
        float dot = (v[i][0] + v[i][1]) + (v[i][2] + v[i][3]);
        float t1 = xxs[i] - 2.0f * dot;
        float d = t1 + cck;
        if (d < bv[i] || (d == bv[i] && k < bi[i])) { bv[i] = d; bi[i] = k; }
      }
    }

    // ---- per-row block reduce
#pragma unroll
    for (int i = 0; i < RB; ++i) { red_v[i][tid] = bv[i]; red_i[i][tid] = bi[i]; }
    __syncthreads();
    for (int gap = 128; gap > 0; gap >>= 1) {
      if (tid < gap) {
#pragma unroll
        for (int i = 0; i < RB; ++i) {
          float o = red_v[i][tid + gap];
          int oi = red_i[i][tid + gap];
          if (o < red_v[i][tid] || (o == red_v[i][tid] && oi < red_i[i][tid])) {
            red_v[i][tid] = o;
            red_i[i][tid] = oi;
          }
        }
      }
      __syncthreads();
    }
    if (tid < nb) idx_out[flagrows[base + tid]] = red_i[tid][0];
    __syncthreads();
  }
}

// ---------------- slim final: quant + loss + hist + one-hot SCATTER ----
__global__ __launch_bounds__(256) void final_k(
    const float* __restrict__ data, const float* __restrict__ cb0,
    const float* __restrict__ cb1, const float* __restrict__ cb2,
    const int* __restrict__ idx0, const int* __restrict__ idx1,
    const int* __restrict__ idx2, float* __restrict__ quant,
    float* __restrict__ enc0, float* __restrict__ enc1,
    float* __restrict__ enc2, double* __restrict__ loss_slots,
    unsigned int* __restrict__ hist) {
  __shared__ double wsum[4];
  const int lane = threadIdx.x & 63;
  const int w = threadIdx.x >> 6;
  const int r = blockIdx.x * 4 + w;
  const int i0 = idx0[r], i1 = idx1[r], i2 = idx2[r];
  const size_t base = (size_t)r * DDIM + lane * 4;
  float4 dv = *(const float4*)(data + base);
  float4 c0v = *(const float4*)(cb0 + (size_t)i0 * DDIM + lane * 4);
  float4 c1v = *(const float4*)(cb1 + (size_t)i1 * DDIM + lane * 4);
  float4 c2v = *(const float4*)(cb2 + (size_t)i2 * DDIM + lane * 4);
  float df[4] = {dv.x, dv.y, dv.z, dv.w};
  float q0f[4] = {c0v.x, c0v.y, c0v.z, c0v.w};
  float q1f[4] = {c1v.x, c1v.y, c1v.z, c1v.w};
  float q2f[4] = {c2v.x, c2v.y, c2v.z, c2v.w};
  float qout[4];
  double lsum = 0.0;
  {
#pragma clang fp contract(off)
#pragma unroll
    for (int j = 0; j < 4; ++j) {
      float x1 = df[j];
      float d1 = q0f[j] - x1;
      float qst1 = x1 + d1;
      float a1 = qst1;
      float x2 = x1 - a1;
      float d2 = q1f[j] - x2;
      float qst2 = x2 + d2;
      float a2 = a1 + qst2;
      float x3 = x1 - a2;
      float d3 = q2f[j] - x3;
      float qst3 = x3 + d3;
      float a3 = a2 + qst3;
      qout[j] = a3;
      lsum += (double)d1 * d1 + (double)d2 * d2 + (double)d3 * d3;
    }
  }
  float4 qv = {qout[0], qout[1], qout[2], qout[3]};
  *(float4*)(quant + base) = qv;

#pragma unroll
  for (int off = 1; off < 64; off <<= 1) lsum += __shfl_xor(lsum, off, 64);
  if (lane == 0) {
    wsum[w] = lsum;
    enc0[(size_t)r * KCODES + i0] = 1.0f;
    atomicAdd(&hist[i0], 1u);
  } else if (lane == 1) {
    enc1[(size_t)r * KCODES + i1] = 1.0f;
    atomicAdd(&hist[KCODES + i1], 1u);
  } else if (lane == 2) {
    enc2[(size_t)r * KCODES + i2] = 1.0f;
    atomicAdd(&hist[2 * KCODES + i2], 1u);
  }
  __syncthreads();
  if (threadIdx.x == 0) {
    double bsum = (wsum[0] + wsum[1]) + (wsum[2] + wsum[3]);
    atomicAdd(&loss_slots[blockIdx.x & (NLOSS - 1)], bsum);
  }
}

// ---------------- scalars ----------------
__global__ void finalize_k(const unsigned int* __restrict__ hist,
                           const double* __restrict__ loss_slots,
                           float* __restrict__ out_scalars) {
  int lane = threadIdx.x;  // 64 threads
  double te = 0.0;
  for (int s = 0; s < NSTAGE; ++s) {
    double e = 0.0;
    for (int j = 0; j < KCODES / 64; ++j) {
      int k = j * 64 + lane;
      float pf = (float)hist[s * KCODES + k] * (1.0f / 65536.0f);
      float sf = __fadd_rn(pf, 1e-10f);
      e += (double)pf * log((double)sf);
    }
#pragma unroll
    for (int off = 1; off < 64; off <<= 1) e += __shfl_xor(e, off, 64);
    te += -e;
  }
  double ls = loss_slots[lane] + loss_slots[64 + lane] +
              loss_slots[128 + lane] + loss_slots[192 + lane];
#pragma unroll
  for (int off = 1; off < 64; off <<= 1) ls += __shfl_xor(ls, off, 64);
  if (lane == 0) {
    double tl = 1.25 * ls * (1.0 / 16777216.0);
    out_scalars[0] = (float)tl;
    out_scalars[1] = (float)te;
  }
}

extern "C" void kernel_launch(void* const* d_in, const int* in_sizes, int n_in,
                              void* d_out, int out_size, void* d_ws, size_t ws_size,
                              hipStream_t stream) {
  const float* data = (const float*)d_in[0];
  const float* cb0 = (const float*)d_in[1];
  const float* cb1 = (const float*)d_in[2];
  const float* cb2 = (const float*)d_in[3];
  const float* cbs[3] = {cb0, cb1, cb2};
  float* out = (float*)d_out;
  float* quant = out;
  float* enc0 = out + (size_t)NROWS * DDIM;
  float* enc1 = enc0 + (size_t)NROWS * KCODES;
  float* enc2 = enc1 + (size_t)NROWS * KCODES;
  float* out_scalars = enc2 + (size_t)NROWS * KCODES;

  // A-image scratch in enc0 output region (memset after stage loop wipes it)
  char* AhG = (char*)enc0;                // 32 MB

  // ws: [0) loss_slots f64x256 | 2048) hist u32x1536 | 8192) flagcnt u32x3 |
  //     8320) flagrows i32[3][65536] | 794752) cc f32x1536 |
  //     800896) idx i32[3][N] | 1587328) Ch frag-bf16 3x256KB (ends 2373760)
  double* loss_slots = (double*)d_ws;
  unsigned int* hist = (unsigned int*)((char*)d_ws + 2048);
  unsigned int* flagcnt = (unsigned int*)((char*)d_ws + 8192);
  int* flagrows = (int*)((char*)d_ws + 8320);
  float* cc = (float*)((char*)d_ws + 794752);
  int* idx0 = (int*)((char*)d_ws + 800896);
  int* idx1 = idx0 + NROWS;
  int* idx2 = idx1 + NROWS;
  int* idxs[3] = {idx0, idx1, idx2};
  unsigned short* Ch = (unsigned short*)((char*)d_ws + 1587328);

  hipMemsetAsync(d_ws, 0, 8320, stream);

  cc_np_k<<<(NSTAGE * KCODES + 255) / 256, 256, 0, stream>>>(cb0, cb1, cb2, cc);
  split_cb_k<<<(NSTAGE * KCODES * 32 + 255) / 256, 256, 0, stream>>>(
      cb0, cb1, cb2, Ch);

  for (int s = 0; s < NSTAGE; ++s) {
    chain_k<<<NROWS * 32 / 256, 256, 0, stream>>>(
        data, cb0, cb1, idx0, idx1, s, AhG);
    gemm_k<<<NROWS / MB, NTH, 0, stream>>>(
        AhG,
        (const unsigned short*)((char*)Ch + (size_t)s * 262144),
        cc + s * KCODES, idxs[s], flagcnt + s, flagrows + s * MAXFLAG);
    refine_k<<<512, 256, 0, stream>>>(
        data, cbs[s], cb0, cb1, idx0, idx1, cc + s * KCODES, s,
        flagcnt + s, flagrows + s * MAXFLAG, idxs[s]);
  }

  // zero enc region (also wipes A-image scratch), then scatter the 1s
  hipMemsetAsync(enc0, 0, (size_t)3 * NROWS * KCODES * sizeof(float), stream);

  final_k<<<NROWS / 4, 256, 0, stream>>>(
      data, cb0, cb1, cb2, idx0, idx1, idx2, quant, enc0, enc1, enc2,
      loss_slots, hist);

  finalize_k<<<1, 64, 0, stream>>>(hist, loss_slots, out_scalars);
}